// Round 2
// baseline (3942.316 us; speedup 1.0000x reference)
//
#include <hip/hip_runtime.h>
#include <math.h>

// Problem constants
#define B_     32
#define T_     512
#define LATENT 64
#define COND   448
#define HIDDEN 1024
#define OUTD   512
#define E_     8
#define INPUT_ 512     // LATENT + COND
#define INTER_ 1536    // LATENT + COND + HIDDEN
#define GATEH  64
#define NTOK   (B_ * T_)   // 16384
#define GB     8           // batches per weight-mix group (wm buffer = GB*fin*fout bf16)
#define NGROUP (B_ / GB)

// bf16 helpers: RNE float->bf16, and unpack 8 packed bf16 (16B) -> 8 floats
static __device__ __forceinline__ unsigned short f2bf(float x) {
    unsigned u = __float_as_uint(x);
    u += 0x7fffu + ((u >> 16) & 1u);
    return (unsigned short)(u >> 16);
}
static __device__ __forceinline__ void unpack8(const int4 r, float* v) {
    const unsigned* p = (const unsigned*)&r;
#pragma unroll
    for (int i = 0; i < 4; ++i) {
        v[2 * i + 0] = __uint_as_float(p[i] << 16);
        v[2 * i + 1] = __uint_as_float(p[i] & 0xffff0000u);
    }
}

// ---------------------------------------------------------------------------
// Gate network: per token, x=[z|c] (512) -> 64 -> 64 -> 8 softmax -> coef.
// One wave per token, 8 tokens per block.
// ---------------------------------------------------------------------------
__global__ __launch_bounds__(512) void gate_kernel(
    const float* __restrict__ z, const float* __restrict__ c,
    const float* __restrict__ gw0, const float* __restrict__ gb0,
    const float* __restrict__ gw1, const float* __restrict__ gb1,
    const float* __restrict__ gw2, const float* __restrict__ gb2,
    float* __restrict__ coef)
{
    __shared__ float sX[8][INPUT_];
    __shared__ float sH[8][GATEH];
    const int wave = threadIdx.x >> 6;
    const int lane = threadIdx.x & 63;
    const int token = blockIdx.x * 8 + wave;

    const float* zrow = z + (size_t)token * LATENT;
    const float* crow = c + (size_t)token * COND;
    for (int i = lane; i < INPUT_; i += 64)
        sX[wave][i] = (i < LATENT) ? zrow[i] : crow[i - LATENT];
    __syncthreads();

    float acc = gb0[lane];
    for (int i = 0; i < INPUT_; ++i)
        acc = fmaf(sX[wave][i], gw0[i * GATEH + lane], acc);
    acc = acc > 0.f ? acc : 0.01f * acc;
    sH[wave][lane] = acc;
    __syncthreads();

    float acc1 = gb1[lane];
    for (int i = 0; i < GATEH; ++i)
        acc1 = fmaf(sH[wave][i], gw1[i * GATEH + lane], acc1);
    acc1 = acc1 > 0.f ? acc1 : 0.01f * acc1;
    __syncthreads();
    sH[wave][lane] = acc1;
    __syncthreads();

    const int e = lane & 7;
    float lg = gb2[e];
    for (int i = 0; i < GATEH; ++i)
        lg = fmaf(sH[wave][i], gw2[i * E_ + e], lg);

    float m = lg;
    for (int off = 1; off < 8; off <<= 1)
        m = fmaxf(m, __shfl_xor(m, off, 8));
    float ex = expf(lg - m);
    float s = ex;
    for (int off = 1; off < 8; off <<= 1)
        s += __shfl_xor(s, off, 8);
    if (lane < 8)
        coef[(size_t)token * E_ + lane] = ex / s;
}

// ---------------------------------------------------------------------------
// Weight mixing for GB batches: wm[b][f] = sum_e coef0[batch0+b][e]*w[e][f],
// stored bf16. Each thread: one float4 of f, 8 expert reads, GB bf16x4 writes.
// ---------------------------------------------------------------------------
__global__ __launch_bounds__(256) void mix_kernel(
    const float* __restrict__ w,          // (E, fin*fout) fp32
    const float* __restrict__ coef,       // (NTOK, 8)
    unsigned short* __restrict__ wm,      // (GB, fin*fout) bf16
    int finfout, int batch0)
{
    __shared__ float sC[GB][E_];
    const int tid = threadIdx.x;
    if (tid < GB * E_)
        sC[tid >> 3][tid & 7] =
            coef[((size_t)(batch0 + (tid >> 3)) * T_) * E_ + (tid & 7)];
    __syncthreads();

    size_t f = ((size_t)blockIdx.x * 256 + tid) * 4;
    if (f >= (size_t)finfout) return;

    float4 we[E_];
#pragma unroll
    for (int e = 0; e < E_; ++e)
        we[e] = *(const float4*)(w + (size_t)e * finfout + f);

#pragma unroll
    for (int b = 0; b < GB; ++b) {
        float4 a = make_float4(0.f, 0.f, 0.f, 0.f);
#pragma unroll
        for (int e = 0; e < E_; ++e) {
            float cc = sC[b][e];
            a.x = fmaf(cc, we[e].x, a.x);
            a.y = fmaf(cc, we[e].y, a.y);
            a.z = fmaf(cc, we[e].z, a.z);
            a.w = fmaf(cc, we[e].w, a.w);
        }
        ushort4 o;
        o.x = f2bf(a.x); o.y = f2bf(a.y); o.z = f2bf(a.z); o.w = f2bf(a.w);
        *(ushort4*)(wm + (size_t)b * finfout + f) = o;
    }
}

// ---------------------------------------------------------------------------
// Per-batch GEMM for GB batches:
//   out[b,t,o] = leaky?( sum_i inp[b,t,i]*wm[b-batch0,i,o]
//                        + sum_e coef[b,t,e]*bias[e,o] )
// A columns: [0,64) -> z fp32, [64,512) -> c fp32, [512,fin) -> prev bf16.
// B = wm bf16. fp32 LDS tiles, fp32 8x8 FMA per thread. Output bf16 or fp32.
// ---------------------------------------------------------------------------
#define BM 128
#define BN 128
#define BK 16
#define PAD 4

__global__ __launch_bounds__(256) void gemm_kernel(
    const float* __restrict__ z,           // (NTOK, 64)
    const float* __restrict__ c,           // (NTOK, 448)
    const unsigned short* __restrict__ prev, // (NTOK, 1024) bf16
    const unsigned short* __restrict__ wm, // (GB, fin, fout) bf16
    const float* __restrict__ bias,        // (E, fout) fp32
    const float* __restrict__ coef,        // (NTOK, 8) fp32
    float* __restrict__ outf,              // fp32 out (layer 4)
    unsigned short* __restrict__ outb,     // bf16 out (layers 0-3), or null
    int fin, int fout, int act, int batch0)
{
    __shared__ float As[BK][BM + PAD];
    __shared__ float Bs[BK][BN + PAD];
    __shared__ float sBias[E_][BN];

    const int tid = threadIdx.x;
    const int tx = tid & 15;
    const int ty = tid >> 4;
    const int b = batch0 + blockIdx.z;
    const int row0 = blockIdx.y * BM;
    const int col0 = blockIdx.x * BN;
    const unsigned short* wmb = wm + (size_t)blockIdx.z * fin * fout;
    const size_t tokbase = (size_t)b * T_;

    {
        int i0 = tid * 4;
        int e = i0 >> 7, n = i0 & 127;
        float4 bv = *(const float4*)(bias + (size_t)e * fout + col0 + n);
        *(float4*)&sBias[e][n] = bv;
    }

    float acc[8][8];
#pragma unroll
    for (int i = 0; i < 8; ++i)
#pragma unroll
        for (int j = 0; j < 8; ++j) acc[i][j] = 0.f;

    const int am = tid >> 1;            // 0..127 (tile row)
    const int ak = (tid & 1) * 8;       // 0 or 8
    const int bk = tid >> 4;            // 0..15
    const int bn = (tid & 15) * 8;      // 0..120

    for (int k0 = 0; k0 < fin; k0 += BK) {
        // ---- A load (8 elems) ----
        float av[8];
        {
            const float* af32 = 0; const unsigned short* abf = 0;
            int astride, acol;
            if (k0 < LATENT)      { af32 = z; astride = LATENT; acol = k0; }
            else if (k0 < INPUT_) { af32 = c; astride = COND;   acol = k0 - LATENT; }
            else                  { abf = prev; astride = HIDDEN; acol = k0 - INPUT_; }
            size_t aoff = (size_t)(tokbase + row0 + am) * astride + acol + ak;
            if (af32) {
                float4 v0 = *(const float4*)(af32 + aoff);
                float4 v1 = *(const float4*)(af32 + aoff + 4);
                av[0] = v0.x; av[1] = v0.y; av[2] = v0.z; av[3] = v0.w;
                av[4] = v1.x; av[5] = v1.y; av[6] = v1.z; av[7] = v1.w;
            } else {
                int4 r = *(const int4*)(abf + aoff);
                unpack8(r, av);
            }
        }
        // ---- B load (8 elems bf16) ----
        float bv[8];
        {
            size_t boff = (size_t)(k0 + bk) * fout + col0 + bn;
            int4 r = *(const int4*)(wmb + boff);
            unpack8(r, bv);
        }

        __syncthreads();
#pragma unroll
        for (int q = 0; q < 8; ++q) As[ak + q][am] = av[q];
        *(float4*)&Bs[bk][bn]     = make_float4(bv[0], bv[1], bv[2], bv[3]);
        *(float4*)&Bs[bk][bn + 4] = make_float4(bv[4], bv[5], bv[6], bv[7]);
        __syncthreads();

#pragma unroll
        for (int k = 0; k < BK; ++k) {
            float4 a0 = *(const float4*)&As[k][ty * 4];
            float4 a1 = *(const float4*)&As[k][64 + ty * 4];
            float4 b0 = *(const float4*)&Bs[k][tx * 4];
            float4 b1 = *(const float4*)&Bs[k][64 + tx * 4];
            float ar[8] = {a0.x, a0.y, a0.z, a0.w, a1.x, a1.y, a1.z, a1.w};
            float br[8] = {b0.x, b0.y, b0.z, b0.w, b1.x, b1.y, b1.z, b1.w};
#pragma unroll
            for (int i = 0; i < 8; ++i)
#pragma unroll
                for (int j = 0; j < 8; ++j)
                    acc[i][j] = fmaf(ar[i], br[j], acc[i][j]);
        }
    }

    // epilogue
#pragma unroll
    for (int ih = 0; ih < 2; ++ih) {
#pragma unroll
        for (int i = 0; i < 4; ++i) {
            int trow = row0 + ih * 64 + ty * 4 + i;
            size_t token = tokbase + trow;
            const float* cf = coef + token * E_;
            float cfr[E_];
#pragma unroll
            for (int e = 0; e < E_; ++e) cfr[e] = cf[e];
#pragma unroll
            for (int jh = 0; jh < 2; ++jh) {
                float o[4];
#pragma unroll
                for (int j = 0; j < 4; ++j) {
                    float v = acc[ih * 4 + i][jh * 4 + j];
                    int col = jh * 64 + tx * 4 + j;
#pragma unroll
                    for (int e = 0; e < E_; ++e)
                        v = fmaf(cfr[e], sBias[e][col], v);
                    if (act) v = v > 0.f ? v : 0.01f * v;
                    o[j] = v;
                }
                size_t off = token * fout + col0 + jh * 64 + tx * 4;
                if (outb) {
                    ushort4 ob;
                    ob.x = f2bf(o[0]); ob.y = f2bf(o[1]);
                    ob.z = f2bf(o[2]); ob.w = f2bf(o[3]);
                    *(ushort4*)(outb + off) = ob;
                } else {
                    *(float4*)(outf + off) = make_float4(o[0], o[1], o[2], o[3]);
                }
            }
        }
    }
}

// ---------------------------------------------------------------------------
// Launch. Workspace (bytes):
//   coef  fp32 NTOK*8           =   512 KB
//   actB  bf16 NTOK*1024        = 33.55 MB
//   wm    bf16 GB*1536*1024     = 25.17 MB
//   total ~59.2 MB.  actA lives in d_out (16384*512 fp32 == 16384*1024 bf16).
// ---------------------------------------------------------------------------
extern "C" void kernel_launch(void* const* d_in, const int* in_sizes, int n_in,
                              void* d_out, int out_size, void* d_ws, size_t ws_size,
                              hipStream_t stream)
{
    const float* z = (const float*)d_in[0];
    const float* c = (const float*)d_in[1];
    const float* w[5]  = {(const float*)d_in[2], (const float*)d_in[4],
                          (const float*)d_in[6], (const float*)d_in[8],
                          (const float*)d_in[10]};
    const float* bs[5] = {(const float*)d_in[3], (const float*)d_in[5],
                          (const float*)d_in[7], (const float*)d_in[9],
                          (const float*)d_in[11]};
    const float* gw0 = (const float*)d_in[12]; const float* gb0 = (const float*)d_in[13];
    const float* gw1 = (const float*)d_in[14]; const float* gb1 = (const float*)d_in[15];
    const float* gw2 = (const float*)d_in[16]; const float* gb2 = (const float*)d_in[17];

    char* wsb = (char*)d_ws;
    float* coef          = (float*)wsb;                          // 512 KB
    unsigned short* actB = (unsigned short*)(wsb + (size_t)512 * 1024);
    unsigned short* wm   = (unsigned short*)(wsb + (size_t)512 * 1024
                                             + (size_t)NTOK * HIDDEN * 2);
    unsigned short* actA = (unsigned short*)d_out;   // d_out doubles as ping buffer

    gate_kernel<<<NTOK / 8, 512, 0, stream>>>(z, c, gw0, gb0, gw1, gb1,
                                              gw2, gb2, coef);

    struct Layer { int fin, fout, act; const unsigned short* in; unsigned short* outb; };
    Layer layers[5] = {
        {INPUT_, HIDDEN, 1, actB /*unused*/, actA},
        {INTER_, HIDDEN, 1, actA, actB},
        {INTER_, HIDDEN, 1, actB, actA},
        {INTER_, HIDDEN, 1, actA, actB},
        {INTER_, OUTD,   0, actB, 0},
    };

    for (int L = 0; L < 5; ++L) {
        int finfout = layers[L].fin * layers[L].fout;
        for (int g = 0; g < NGROUP; ++g) {
            mix_kernel<<<finfout / 1024, 256, 0, stream>>>(
                w[L], coef, wm, finfout, g * GB);
            gemm_kernel<<<dim3(layers[L].fout / BN, T_ / BM, GB), 256, 0, stream>>>(
                z, c, layers[L].in, wm, bs[L], coef,
                (float*)d_out, layers[L].outb,
                layers[L].fin, layers[L].fout, layers[L].act, g * GB);
        }
    }
}

// Round 3
// 826.642 us; speedup vs baseline: 4.7691x; 4.7691x over previous
//
#include <hip/hip_runtime.h>
#include <math.h>

// Problem constants
#define B_     32
#define T_     512
#define LATENT 64
#define COND   448
#define HIDDEN 1024
#define OUTD   512
#define E_     8
#define INPUT_ 512     // LATENT + COND
#define INTER_ 1536    // LATENT + COND + HIDDEN
#define GATEH  64
#define NTOK   (B_ * T_)   // 16384

typedef __attribute__((ext_vector_type(8))) short short8;   // bf16x8 MFMA A/B frag
typedef __attribute__((ext_vector_type(4))) float f32x4;    // MFMA C/D frag

static __device__ __forceinline__ unsigned short f2bf(float x) {
    unsigned u = __float_as_uint(x);
    u += 0x7fffu + ((u >> 16) & 1u);
    return (unsigned short)(u >> 16);
}

// ---------------------------------------------------------------------------
// Gate network + xz(bf16) materialization.
// One wave per token, 8 tokens per block.
// ---------------------------------------------------------------------------
__global__ __launch_bounds__(512) void gate_kernel(
    const float* __restrict__ z, const float* __restrict__ c,
    const float* __restrict__ gw0, const float* __restrict__ gb0,
    const float* __restrict__ gw1, const float* __restrict__ gb1,
    const float* __restrict__ gw2, const float* __restrict__ gb2,
    float* __restrict__ coef, unsigned short* __restrict__ xzb)
{
    __shared__ float sX[8][INPUT_];
    __shared__ float sH[8][GATEH];
    const int wave = threadIdx.x >> 6;
    const int lane = threadIdx.x & 63;
    const int token = blockIdx.x * 8 + wave;

    const float* zrow = z + (size_t)token * LATENT;
    const float* crow = c + (size_t)token * COND;
    unsigned short* xrow = xzb + (size_t)token * INPUT_;
    for (int i = lane; i < INPUT_; i += 64) {
        float v = (i < LATENT) ? zrow[i] : crow[i - LATENT];
        sX[wave][i] = v;
        xrow[i] = f2bf(v);
    }
    __syncthreads();

    float acc = gb0[lane];
    for (int i = 0; i < INPUT_; ++i)
        acc = fmaf(sX[wave][i], gw0[i * GATEH + lane], acc);
    acc = acc > 0.f ? acc : 0.01f * acc;
    sH[wave][lane] = acc;
    __syncthreads();

    float acc1 = gb1[lane];
    for (int i = 0; i < GATEH; ++i)
        acc1 = fmaf(sH[wave][i], gw1[i * GATEH + lane], acc1);
    acc1 = acc1 > 0.f ? acc1 : 0.01f * acc1;
    __syncthreads();
    sH[wave][lane] = acc1;
    __syncthreads();

    const int e = lane & 7;
    float lg = gb2[e];
    for (int i = 0; i < GATEH; ++i)
        lg = fmaf(sH[wave][i], gw2[i * E_ + e], lg);

    float m = lg;
    for (int off = 1; off < 8; off <<= 1)
        m = fmaxf(m, __shfl_xor(m, off, 8));
    float ex = expf(lg - m);
    float s = ex;
    for (int off = 1; off < 8; off <<= 1)
        s += __shfl_xor(s, off, 8);
    if (lane < 8)
        coef[(size_t)token * E_ + lane] = ex / s;
}

// ---------------------------------------------------------------------------
// Transpose-mix: wmT[b][o][i] = bf16( sum_e coef0[batch0+b][e] * w[e][i][o] )
// Tile 32(i) x 64(o); 8-expert fp32 tile staged in LDS (pad 66 -> 2-way max),
// then per-batch mix with writes contiguous along i (ushort8 = 16B).
// ---------------------------------------------------------------------------
#define MI 32
#define MO 64
#define MP 66

__global__ __launch_bounds__(256) void mixT_kernel(
    const float* __restrict__ w,          // (E, fin, fout) fp32
    const float* __restrict__ coef,       // (NTOK, 8)
    unsigned short* __restrict__ wmT,     // (gb, fout, fin) bf16
    int fin, int fout, int gb, int batch0)
{
    __shared__ float sW[E_][MI][MP];
    __shared__ float sC[B_][E_];
    const int t = threadIdx.x;
    const int nbi = fin / MI;
    const int i0 = (blockIdx.x % nbi) * MI;
    const int o0 = (blockIdx.x / nbi) * MO;

    if (t < gb * E_)
        sC[t >> 3][t & 7] = coef[(size_t)(batch0 + (t >> 3)) * T_ * E_ + (t & 7)];

    // phase 1: stage 8 x 32 x 64 fp32 as float2 (32 per thread), coalesced
#pragma unroll
    for (int r = 0; r < 32; ++r) {
        int idx = r * 256 + t;
        int o2 = idx & 31;
        int i  = (idx >> 5) & 31;
        int e  = idx >> 10;
        float2 v = *(const float2*)(w + (size_t)e * fin * fout
                                      + (size_t)(i0 + i) * fout + o0 + o2 * 2);
        *(float2*)&sW[e][i][o2 * 2] = v;
    }
    __syncthreads();

    // phase 2: thread -> (o = t>>2, i8 = (t&3)*8); per batch, 8 outputs along i
    const int o  = t >> 2;
    const int i8 = (t & 3) * 8;
    for (int b = 0; b < gb; ++b) {
        float v[8];
#pragma unroll
        for (int j = 0; j < 8; ++j) v[j] = 0.f;
#pragma unroll
        for (int e = 0; e < E_; ++e) {
            float cc = sC[b][e];
#pragma unroll
            for (int j = 0; j < 8; ++j)
                v[j] = fmaf(cc, sW[e][i8 + j][o], v[j]);
        }
        unsigned short u[8];
#pragma unroll
        for (int j = 0; j < 8; ++j) u[j] = f2bf(v[j]);
        *(int4*)(wmT + ((size_t)b * fout + o0 + o) * fin + i0 + i8) = *(const int4*)u;
    }
}

// ---------------------------------------------------------------------------
// MFMA GEMM (m97 structure): 128x128 tile, BK=32, mfma_f32_16x16x32_bf16.
// A: [m][k] rows of 32 bf16 (xz for k<512, prev for k>=512).
// B: wmT[b][n][k] -> staged identically. global_load_lds width 16.
// 4 waves, each 64x64 (4x4 frags). Epilogue: coef-dot-bias + leaky + store.
// ---------------------------------------------------------------------------
__global__ __launch_bounds__(256) void gemm_kernel(
    const unsigned short* __restrict__ xz,    // (NTOK, 512) bf16
    const unsigned short* __restrict__ prev,  // (NTOK, 1024) bf16
    const unsigned short* __restrict__ wmT,   // (gb, fout, fin) bf16
    const float* __restrict__ bias,           // (E, fout)
    const float* __restrict__ coef,           // (NTOK, 8)
    float* __restrict__ outf,                 // fp32 out (layer 4)
    unsigned short* __restrict__ outb,        // bf16 out (layers 0-3), or null
    int fin, int fout, int act, int batch0)
{
    __shared__ __align__(16) unsigned short As[128 * 32];
    __shared__ __align__(16) unsigned short Bs[128 * 32];
    __shared__ float sBias[E_][128];
    __shared__ float sCoef[128][8];

    const int tid = threadIdx.x;
    const int lane = tid & 63;
    const int wv = tid >> 6;
    const int row0 = blockIdx.y * 128;
    const int col0 = blockIdx.x * 128;
    const size_t tokbase = (size_t)(batch0 + blockIdx.z) * T_;
    const unsigned short* wmb = wmT + (size_t)blockIdx.z * fin * fout;

    // stage bias (8x128) and coef (128x8) once
    {
        int e = tid >> 5, n = (tid & 31) * 4;
        *(float4*)&sBias[e][n] = *(const float4*)(bias + (size_t)e * fout + col0 + n);
        int r = tid >> 1, c4 = (tid & 1) * 4;
        *(float4*)&sCoef[r][c4] = *(const float4*)(coef + (tokbase + row0 + r) * E_ + c4);
    }

    f32x4 acc[4][4];
#pragma unroll
    for (int im = 0; im < 4; ++im)
#pragma unroll
        for (int in = 0; in < 4; ++in)
            acc[im][in] = (f32x4){0.f, 0.f, 0.f, 0.f};

    const int lrow = lane >> 2;       // row within 16-row chunk
    const int lk8  = (lane & 3) * 8;  // k offset (elems)
    const int wm0 = (wv & 1) * 64, wn0 = (wv >> 1) * 64;
    const int fr = lane & 15, fq = lane >> 4;

    for (int k0 = 0; k0 < fin; k0 += 32) {
        const unsigned short* abase; int astr, acol;
        if (k0 < INPUT_) { abase = xz;   astr = INPUT_; acol = k0; }
        else             { abase = prev; astr = HIDDEN; acol = k0 - INPUT_; }

        __syncthreads();   // previous iteration's frag reads complete
#pragma unroll
        for (int q = 0; q < 4; ++q) {
            int ch = wv * 4 + q;   // wave-uniform chunk id; 0-7 A, 8-15 B
            const unsigned short* src;
            unsigned short* dst;
            if (ch < 8) {
                int m = ch * 16 + lrow;
                src = abase + (tokbase + row0 + m) * astr + acol + lk8;
                dst = As + ch * 512;
            } else {
                int n = (ch - 8) * 16 + lrow;
                src = wmb + (size_t)(col0 + n) * fin + k0 + lk8;
                dst = Bs + (ch - 8) * 512;
            }
            __builtin_amdgcn_global_load_lds(
                (const __attribute__((address_space(1))) unsigned int*)(const void*)src,
                (__attribute__((address_space(3))) unsigned int*)(void*)dst,
                16, 0, 0);
        }
        __syncthreads();   // drains vmcnt(0): staged data visible

        short8 af[4], bfv[4];
#pragma unroll
        for (int im = 0; im < 4; ++im)
            af[im] = *(const short8*)(As + (wm0 + im * 16 + fr) * 32 + fq * 8);
#pragma unroll
        for (int in = 0; in < 4; ++in)
            bfv[in] = *(const short8*)(Bs + (wn0 + in * 16 + fr) * 32 + fq * 8);
#pragma unroll
        for (int im = 0; im < 4; ++im)
#pragma unroll
            for (int in = 0; in < 4; ++in)
                acc[im][in] = __builtin_amdgcn_mfma_f32_16x16x32_bf16(
                    af[im], bfv[in], acc[im][in], 0, 0, 0);
    }

    // epilogue: C/D layout col=lane&15, row=quad*4+reg
#pragma unroll
    for (int im = 0; im < 4; ++im) {
#pragma unroll
        for (int in = 0; in < 4; ++in) {
#pragma unroll
            for (int reg = 0; reg < 4; ++reg) {
                int r = wm0 + im * 16 + fq * 4 + reg;
                int col = wn0 + in * 16 + fr;
                float v = acc[im][in][reg];
#pragma unroll
                for (int e = 0; e < E_; ++e)
                    v = fmaf(sCoef[r][e], sBias[e][col], v);
                if (act) v = v > 0.f ? v : 0.01f * v;
                size_t off = (tokbase + row0 + r) * fout + col0 + col;
                if (outb) outb[off] = f2bf(v);
                else      outf[off] = v;
            }
        }
    }
}

// ---------------------------------------------------------------------------
// Launch. Batch-group size chosen from ws_size:
//   GB=32: xz(16.8M) + coef(0.5M) + actB(33.6M) + actA(33.6M) + wmT(100.7M)
//   GB=8 : xz + coef + actB + wmT(25.2M); actA aliases d_out
//   GB=2 : xz + coef + actB + wmT(6.3M);  actA aliases d_out  (57.1 MB)
// ---------------------------------------------------------------------------
extern "C" void kernel_launch(void* const* d_in, const int* in_sizes, int n_in,
                              void* d_out, int out_size, void* d_ws, size_t ws_size,
                              hipStream_t stream)
{
    const float* z = (const float*)d_in[0];
    const float* c = (const float*)d_in[1];
    const float* w[5]  = {(const float*)d_in[2], (const float*)d_in[4],
                          (const float*)d_in[6], (const float*)d_in[8],
                          (const float*)d_in[10]};
    const float* bs[5] = {(const float*)d_in[3], (const float*)d_in[5],
                          (const float*)d_in[7], (const float*)d_in[9],
                          (const float*)d_in[11]};
    const float* gw0 = (const float*)d_in[12]; const float* gb0 = (const float*)d_in[13];
    const float* gw1 = (const float*)d_in[14]; const float* gb1 = (const float*)d_in[15];
    const float* gw2 = (const float*)d_in[16]; const float* gb2 = (const float*)d_in[17];

    const size_t xz_b   = (size_t)NTOK * INPUT_ * 2;
    const size_t coef_b = (size_t)NTOK * E_ * 4;
    const size_t act_b  = (size_t)NTOK * HIDDEN * 2;
    const size_t wmun   = (size_t)INTER_ * HIDDEN * 2;   // per-batch wmT bytes (max)

    char* p = (char*)d_ws;
    unsigned short* xzb  = (unsigned short*)p;            p += xz_b;
    float*          coef = (float*)p;                     p += coef_b;
    unsigned short* actB = (unsigned short*)p;            p += act_b;

    int gb;
    unsigned short* actA;
    unsigned short* wmT;
    size_t base = xz_b + coef_b + act_b;
    if (ws_size >= base + act_b + 32 * wmun) {
        gb = 32; actA = (unsigned short*)p; p += act_b; wmT = (unsigned short*)p;
    } else if (ws_size >= base + 8 * wmun) {
        gb = 8;  actA = (unsigned short*)d_out; wmT = (unsigned short*)p;
    } else {
        gb = 2;  actA = (unsigned short*)d_out; wmT = (unsigned short*)p;
    }

    gate_kernel<<<NTOK / 8, 512, 0, stream>>>(z, c, gw0, gb0, gw1, gb1,
                                              gw2, gb2, coef, xzb);

    struct L { int fin, fout, act; const unsigned short* in; unsigned short* outb; };
    L Ls[5] = {
        {INPUT_, HIDDEN, 1, actB /*unused*/, actA},
        {INTER_, HIDDEN, 1, actA, actB},
        {INTER_, HIDDEN, 1, actB, actA},
        {INTER_, HIDDEN, 1, actA, actB},
        {INTER_, OUTD,   0, actB, 0},
    };

    for (int Li = 0; Li < 5; ++Li) {
        int fin = Ls[Li].fin, fout = Ls[Li].fout;
        int nblk = (fin / MI) * (fout / MO);
        for (int g = 0; g < B_; g += gb) {
            mixT_kernel<<<nblk, 256, 0, stream>>>(w[Li], coef, wmT, fin, fout, gb, g);
            gemm_kernel<<<dim3(fout / 128, T_ / 128, gb), 256, 0, stream>>>(
                xzb, Ls[Li].in, wmT, bs[Li], coef,
                (float*)d_out, Ls[Li].outb, fin, fout, Ls[Li].act, g);
        }
    }
}

// Round 4
// 803.338 us; speedup vs baseline: 4.9074x; 1.0290x over previous
//
#include <hip/hip_runtime.h>
#include <math.h>

// Problem constants
#define B_     32
#define T_     512
#define LATENT 64
#define COND   448
#define HIDDEN 1024
#define OUTD   512
#define E_     8
#define INPUT_ 512     // LATENT + COND
#define INTER_ 1536    // LATENT + COND + HIDDEN
#define GATEH  64
#define NTOK   (B_ * T_)   // 16384
#define KTAIL  32          // bias-mix folded into K as one extra 32-chunk

typedef __attribute__((ext_vector_type(8))) short short8;   // bf16x8 MFMA A/B frag
typedef __attribute__((ext_vector_type(4))) float f32x4;    // MFMA C/D frag

static __device__ __forceinline__ unsigned short f2bf(float x) {
    unsigned u = __float_as_uint(x);
    u += 0x7fffu + ((u >> 16) & 1u);
    return (unsigned short)(u >> 16);
}

// ---------------------------------------------------------------------------
// Gate network. Emits: coef fp32 (for mixT), coefpad bf16 (NTOK x 32:
// 8 coefs + 24 zeros, the GEMM K-tail A-source), xz bf16.
// ---------------------------------------------------------------------------
__global__ __launch_bounds__(512) void gate_kernel(
    const float* __restrict__ z, const float* __restrict__ c,
    const float* __restrict__ gw0, const float* __restrict__ gb0,
    const float* __restrict__ gw1, const float* __restrict__ gb1,
    const float* __restrict__ gw2, const float* __restrict__ gb2,
    float* __restrict__ coef, unsigned short* __restrict__ coefpad,
    unsigned short* __restrict__ xzb)
{
    __shared__ float sX[8][INPUT_];
    __shared__ float sH[8][GATEH];
    const int wave = threadIdx.x >> 6;
    const int lane = threadIdx.x & 63;
    const int token = blockIdx.x * 8 + wave;

    const float* zrow = z + (size_t)token * LATENT;
    const float* crow = c + (size_t)token * COND;
    unsigned short* xrow = xzb + (size_t)token * INPUT_;
    for (int i = lane; i < INPUT_; i += 64) {
        float v = (i < LATENT) ? zrow[i] : crow[i - LATENT];
        sX[wave][i] = v;
        xrow[i] = f2bf(v);
    }
    __syncthreads();

    float acc = gb0[lane];
    for (int i = 0; i < INPUT_; ++i)
        acc = fmaf(sX[wave][i], gw0[i * GATEH + lane], acc);
    acc = acc > 0.f ? acc : 0.01f * acc;
    sH[wave][lane] = acc;
    __syncthreads();

    float acc1 = gb1[lane];
    for (int i = 0; i < GATEH; ++i)
        acc1 = fmaf(sH[wave][i], gw1[i * GATEH + lane], acc1);
    acc1 = acc1 > 0.f ? acc1 : 0.01f * acc1;
    __syncthreads();
    sH[wave][lane] = acc1;
    __syncthreads();

    const int e = lane & 7;
    float lg = gb2[e];
    for (int i = 0; i < GATEH; ++i)
        lg = fmaf(sH[wave][i], gw2[i * E_ + e], lg);

    float m = lg;
    for (int off = 1; off < 8; off <<= 1)
        m = fmaxf(m, __shfl_xor(m, off, 8));
    float ex = expf(lg - m);
    float s = ex;
    for (int off = 1; off < 8; off <<= 1)
        s += __shfl_xor(s, off, 8);
    float cv = ex / s;
    if (lane < 8) coef[(size_t)token * E_ + lane] = cv;
    if (lane < KTAIL)
        coefpad[(size_t)token * KTAIL + lane] = (lane < 8) ? f2bf(cv) : 0;
}

// ---------------------------------------------------------------------------
// Transpose-mix: wmT[b][o][i] = bf16( sum_e coef0[batch0+b][e] * w[e][i][o] )
// for i < fin; K-tail rows i in [fin, fin+32): bias[e][o] (e<8) else 0.
// Tile 32(i) x 64(o). Scalar LDS staging with pad 65 -> all phases <=2-way.
// ---------------------------------------------------------------------------
#define MI 32
#define MO 64
#define MP 65

__global__ __launch_bounds__(256) void mixT_kernel(
    const float* __restrict__ w,          // (E, fin, fout) fp32
    const float* __restrict__ bias,       // (E, fout) fp32
    const float* __restrict__ coef,       // (NTOK, 8)
    unsigned short* __restrict__ wmT,     // (gb, fout, fin+32) bf16
    int fin, int fout, int gb, int batch0)
{
    __shared__ float sW[E_][MI][MP];
    __shared__ float sC[B_][E_];
    const int t = threadIdx.x;
    const int fin_tot = fin + KTAIL;
    const int nbi = fin / MI;
    const int i0 = (blockIdx.x % nbi) * MI;
    const int o0 = (blockIdx.x / nbi) * MO;

    if (t < gb * E_)
        sC[t >> 3][t & 7] = coef[(size_t)(batch0 + (t >> 3)) * T_ * E_ + (t & 7)];

    // phase 1: stage 8 x 32 x 64 fp32, scalar (bank = (i+o)%32, 2-way free)
#pragma unroll
    for (int r = 0; r < 64; ++r) {
        int idx = r * 256 + t;
        int o = idx & 63;
        int i = (idx >> 6) & 31;
        int e = idx >> 11;
        sW[e][i][o] = w[(size_t)e * fin * fout + (size_t)(i0 + i) * fout + o0 + o];
    }
    __syncthreads();

    // phase 2: thread -> (o = t>>2, i8 = (t&3)*8); per batch, 8 outputs along i
    const int o  = t >> 2;
    const int i8 = (t & 3) * 8;
    for (int b = 0; b < gb; ++b) {
        float v[8];
#pragma unroll
        for (int j = 0; j < 8; ++j) v[j] = 0.f;
#pragma unroll
        for (int e = 0; e < E_; ++e) {
            float cc = sC[b][e];
#pragma unroll
            for (int j = 0; j < 8; ++j)
                v[j] = fmaf(cc, sW[e][i8 + j][o], v[j]);
        }
        unsigned short u[8];
#pragma unroll
        for (int j = 0; j < 8; ++j) u[j] = f2bf(v[j]);
        *(int4*)(wmT + ((size_t)b * fout + o0 + o) * fin_tot + i0 + i8) = *(const int4*)u;
    }

    // K-tail (only blocks with i0 == 0): rows [fin, fin+32) = bias | zeros
    if (i0 == 0) {
        const int jj = t & 3;
        unsigned short u[8];
#pragma unroll
        for (int q = 0; q < 8; ++q)
            u[q] = (jj == 0) ? f2bf(bias[(size_t)q * fout + o0 + o]) : 0;
        for (int b = 0; b < gb; ++b)
            *(int4*)(wmT + ((size_t)b * fout + o0 + o) * fin_tot + fin + jj * 8) =
                *(const int4*)u;
    }
}

// ---------------------------------------------------------------------------
// MFMA GEMM: 256x128 tile, BK=32, mfma_f32_16x16x32_bf16, 4 waves (2x2),
// each wave 128x64 (8x4 frags). A: xz / prev / coefpad (K-tail).
// B: wmT[b][n][k], k includes bias tail. global_load_lds width 16.
// Epilogue: leaky + store only (bias already in accumulator).
// ---------------------------------------------------------------------------
__global__ __launch_bounds__(256, 2) void gemm_kernel(
    const unsigned short* __restrict__ xz,      // (NTOK, 512) bf16
    const unsigned short* __restrict__ prev,    // (NTOK, 1024) bf16
    const unsigned short* __restrict__ wmT,     // (gb, fout, fin_tot) bf16
    const unsigned short* __restrict__ coefpad, // (NTOK, 32) bf16
    float* __restrict__ outf,                   // fp32 out (layer 4)
    unsigned short* __restrict__ outb,          // bf16 out (layers 0-3), or null
    int fin_tot, int fout, int act, int batch0)
{
    __shared__ __align__(16) unsigned short As[256 * 32];   // 16 KB
    __shared__ __align__(16) unsigned short Bs[128 * 32];   // 8 KB

    const int tid = threadIdx.x;
    const int lane = tid & 63;
    const int wv = tid >> 6;
    const int row0 = blockIdx.y * 256;
    const int col0 = blockIdx.x * 128;
    const size_t tokbase = (size_t)(batch0 + blockIdx.z) * T_;
    const unsigned short* wmb = wmT + (size_t)blockIdx.z * fin_tot * fout;

    f32x4 acc[8][4];
#pragma unroll
    for (int im = 0; im < 8; ++im)
#pragma unroll
        for (int in = 0; in < 4; ++in)
            acc[im][in] = (f32x4){0.f, 0.f, 0.f, 0.f};

    const int lrow = lane >> 2;       // row within 16-row chunk
    const int lk8  = (lane & 3) * 8;  // k offset (elems)
    const int wm0 = (wv & 1) * 128, wn0 = (wv >> 1) * 64;
    const int fr = lane & 15, fq = lane >> 4;
    const int ktail0 = fin_tot - KTAIL;

    for (int k0 = 0; k0 < fin_tot; k0 += 32) {
        const unsigned short* abase; int astr, acol;
        if (k0 < INPUT_)       { abase = xz;      astr = INPUT_; acol = k0; }
        else if (k0 < ktail0)  { abase = prev;    astr = HIDDEN; acol = k0 - INPUT_; }
        else                   { abase = coefpad; astr = KTAIL;  acol = 0; }

        __syncthreads();   // previous iteration's frag reads complete
#pragma unroll
        for (int q = 0; q < 6; ++q) {
            int ch = wv * 6 + q;   // wave-uniform; 0-15 A chunks, 16-23 B chunks
            const unsigned short* src;
            unsigned short* dst;
            if (ch < 16) {
                int m = ch * 16 + lrow;
                src = abase + (tokbase + row0 + m) * astr + acol + lk8;
                dst = As + ch * 512;
            } else {
                int n = (ch - 16) * 16 + lrow;
                src = wmb + (size_t)(col0 + n) * fin_tot + k0 + lk8;
                dst = Bs + (ch - 16) * 512;
            }
            __builtin_amdgcn_global_load_lds(
                (const __attribute__((address_space(1))) unsigned int*)(const void*)src,
                (__attribute__((address_space(3))) unsigned int*)(void*)dst,
                16, 0, 0);
        }
        __syncthreads();   // drains vmcnt(0): staged data visible

        short8 af[8], bfv[4];
#pragma unroll
        for (int im = 0; im < 8; ++im)
            af[im] = *(const short8*)(As + (wm0 + im * 16 + fr) * 32 + fq * 8);
#pragma unroll
        for (int in = 0; in < 4; ++in)
            bfv[in] = *(const short8*)(Bs + (wn0 + in * 16 + fr) * 32 + fq * 8);
#pragma unroll
        for (int im = 0; im < 8; ++im)
#pragma unroll
            for (int in = 0; in < 4; ++in)
                acc[im][in] = __builtin_amdgcn_mfma_f32_16x16x32_bf16(
                    af[im], bfv[in], acc[im][in], 0, 0, 0);
    }

    // epilogue: C/D layout col=lane&15, row=quad*4+reg; leaky + store
#pragma unroll
    for (int im = 0; im < 8; ++im) {
#pragma unroll
        for (int in = 0; in < 4; ++in) {
#pragma unroll
            for (int reg = 0; reg < 4; ++reg) {
                int r = wm0 + im * 16 + fq * 4 + reg;
                int col = wn0 + in * 16 + fr;
                float v = acc[im][in][reg];
                if (act) v = v > 0.f ? v : 0.01f * v;
                size_t off = (tokbase + row0 + r) * fout + col0 + col;
                if (outb) outb[off] = f2bf(v);
                else      outf[off] = v;
            }
        }
    }
}

// ---------------------------------------------------------------------------
// Launch. Workspace (bytes):
//   xz 16.8M | coef 0.5M | coefpad 1.0M | actB 33.6M  (base 51.9M)
//   gb=32: + actA 33.6M + wmT 32*1024*1568*2 = 102.8M  -> ~188.3M
//   gb=8 : + wmT 25.7M (actA = d_out)                  -> ~77.6M
//   gb=2 : + wmT 6.4M  (actA = d_out)                  -> ~58.3M
// ---------------------------------------------------------------------------
extern "C" void kernel_launch(void* const* d_in, const int* in_sizes, int n_in,
                              void* d_out, int out_size, void* d_ws, size_t ws_size,
                              hipStream_t stream)
{
    const float* z = (const float*)d_in[0];
    const float* c = (const float*)d_in[1];
    const float* w[5]  = {(const float*)d_in[2], (const float*)d_in[4],
                          (const float*)d_in[6], (const float*)d_in[8],
                          (const float*)d_in[10]};
    const float* bs[5] = {(const float*)d_in[3], (const float*)d_in[5],
                          (const float*)d_in[7], (const float*)d_in[9],
                          (const float*)d_in[11]};
    const float* gw0 = (const float*)d_in[12]; const float* gb0 = (const float*)d_in[13];
    const float* gw1 = (const float*)d_in[14]; const float* gb1 = (const float*)d_in[15];
    const float* gw2 = (const float*)d_in[16]; const float* gb2 = (const float*)d_in[17];

    const size_t xz_b   = (size_t)NTOK * INPUT_ * 2;
    const size_t coef_b = (size_t)NTOK * E_ * 4;
    const size_t cpad_b = (size_t)NTOK * KTAIL * 2;
    const size_t act_b  = (size_t)NTOK * HIDDEN * 2;
    const size_t wmun   = (size_t)(INTER_ + KTAIL) * HIDDEN * 2;  // per-batch max

    char* p = (char*)d_ws;
    unsigned short* xzb   = (unsigned short*)p;  p += xz_b;
    float*          coef  = (float*)p;           p += coef_b;
    unsigned short* cpad  = (unsigned short*)p;  p += cpad_b;
    unsigned short* actB  = (unsigned short*)p;  p += act_b;

    int gb;
    unsigned short* actA;
    unsigned short* wmT;
    size_t base = xz_b + coef_b + cpad_b + act_b;
    if (ws_size >= base + act_b + 32 * wmun) {
        gb = 32; actA = (unsigned short*)p; p += act_b; wmT = (unsigned short*)p;
    } else if (ws_size >= base + 8 * wmun) {
        gb = 8;  actA = (unsigned short*)d_out; wmT = (unsigned short*)p;
    } else {
        gb = 2;  actA = (unsigned short*)d_out; wmT = (unsigned short*)p;
    }

    gate_kernel<<<NTOK / 8, 512, 0, stream>>>(z, c, gw0, gb0, gw1, gb1,
                                              gw2, gb2, coef, cpad, xzb);

    struct L { int fin, fout, act; const unsigned short* in; unsigned short* outb; };
    L Ls[5] = {
        {INPUT_, HIDDEN, 1, actB /*unused*/, actA},
        {INTER_, HIDDEN, 1, actA, actB},
        {INTER_, HIDDEN, 1, actB, actA},
        {INTER_, HIDDEN, 1, actA, actB},
        {INTER_, OUTD,   0, actB, 0},
    };

    for (int Li = 0; Li < 5; ++Li) {
        int fin = Ls[Li].fin, fout = Ls[Li].fout;
        int nblk = (fin / MI) * (fout / MO);
        for (int g = 0; g < B_; g += gb) {
            mixT_kernel<<<nblk, 256, 0, stream>>>(
                w[Li], bs[Li], coef, wmT, fin, fout, gb, g);
            gemm_kernel<<<dim3(fout / 128, T_ / 256, gb), 256, 0, stream>>>(
                xzb, Ls[Li].in, wmT, cpad,
                (float*)d_out, Ls[Li].outb, fin + KTAIL, fout, Ls[Li].act, g);
        }
    }
}

// Round 5
// 717.211 us; speedup vs baseline: 5.4967x; 1.1201x over previous
//
#include <hip/hip_runtime.h>
#include <math.h>

// Problem constants
#define B_     32
#define T_     512
#define LATENT 64
#define COND   448
#define HIDDEN 1024
#define OUTD   512
#define E_     8
#define INPUT_ 512     // LATENT + COND
#define INTER_ 1536    // LATENT + COND + HIDDEN
#define GATEH  64
#define NTOK   (B_ * T_)   // 16384
#define KTAIL  32          // bias-mix folded into K as one extra 32-chunk

typedef __attribute__((ext_vector_type(8))) short short8;   // bf16x8 MFMA A/B frag
typedef __attribute__((ext_vector_type(4))) float f32x4;    // MFMA C/D frag

static __device__ __forceinline__ unsigned short f2bf(float x) {
    unsigned u = __float_as_uint(x);
    u += 0x7fffu + ((u >> 16) & 1u);
    return (unsigned short)(u >> 16);
}

// ---------------------------------------------------------------------------
// wprep: transpose gate weights to bf16 [n][k] rows for MFMA B-operands.
// gw0T: 64 x 512, gw1T: 64 x 64.
// ---------------------------------------------------------------------------
__global__ __launch_bounds__(256) void wprep_kernel(
    const float* __restrict__ gw0, const float* __restrict__ gw1,
    unsigned short* __restrict__ gw0T, unsigned short* __restrict__ gw1T)
{
    int idx = blockIdx.x * 256 + threadIdx.x;
    if (idx < GATEH * INPUT_) {
        int n = idx >> 9, k = idx & 511;
        gw0T[n * INPUT_ + k] = f2bf(gw0[k * GATEH + n]);
    } else {
        int i2 = idx - GATEH * INPUT_;
        if (i2 < GATEH * GATEH) {
            int n = i2 >> 6, k = i2 & 63;
            gw1T[n * GATEH + k] = f2bf(gw1[k * GATEH + n]);
        }
    }
}

// ---------------------------------------------------------------------------
// Gate (MFMA): 64 tokens/block, 256 threads (4 waves).
// Phase 0: convert z|c -> xz bf16 (global), also consumed as MFMA A.
// g0: [64x512]@[512x64] via mfma_16x16x32_bf16 (B from gw0T, global).
// g1: [64x64]@[64x64] (A from LDS Hb, B from gw1T).
// g2 + softmax: vector fp32. Writes coef fp32 and coefpad bf16 (8 + 24 zeros).
// ---------------------------------------------------------------------------
__global__ __launch_bounds__(256) void gate_kernel(
    const float* __restrict__ z, const float* __restrict__ c,
    const float* __restrict__ gb0,
    const float* __restrict__ gb1,
    const float* __restrict__ gw2, const float* __restrict__ gb2,
    const unsigned short* __restrict__ gw0T,
    const unsigned short* __restrict__ gw1T,
    float* __restrict__ coef, unsigned short* __restrict__ coefpad,
    unsigned short* __restrict__ xzb)
{
    __shared__ unsigned short Hb[GATEH][72];   // g0 out, bf16, pad->2-way free
    __shared__ float H2[GATEH][65];            // g1 out, fp32
    __shared__ float sLg[GATEH][E_];           // logits

    const int tid = threadIdx.x;
    const int lane = tid & 63;
    const int wv = tid >> 6;
    const int tok0 = blockIdx.x * 64;

    // ---- phase 0: z|c -> xz bf16 ----
#pragma unroll
    for (int i = 0; i < 4; ++i) {              // z: 64 tok x 64
        int idx = i * 256 + tid;
        int tr = idx >> 4, c4 = (idx & 15) * 4;
        float4 v = *(const float4*)(z + ((size_t)(tok0 + tr) * LATENT) + c4);
        ushort4 o = {f2bf(v.x), f2bf(v.y), f2bf(v.z), f2bf(v.w)};
        *(ushort4*)(xzb + (size_t)(tok0 + tr) * INPUT_ + c4) = o;
    }
#pragma unroll
    for (int i = 0; i < 28; ++i) {             // c: 64 tok x 448
        int idx = i * 256 + tid;
        int tr = idx / 112, c4 = (idx % 112) * 4;
        float4 v = *(const float4*)(c + ((size_t)(tok0 + tr) * COND) + c4);
        ushort4 o = {f2bf(v.x), f2bf(v.y), f2bf(v.z), f2bf(v.w)};
        *(ushort4*)(xzb + (size_t)(tok0 + tr) * INPUT_ + LATENT + c4) = o;
    }
    __threadfence_block();
    __syncthreads();

    const int fr = lane & 15, fq = lane >> 4;
    const int wm0 = (wv & 1) * 32, wn0 = (wv >> 1) * 32;

    // ---- g0 MFMA ----
    f32x4 acc[2][2];
#pragma unroll
    for (int im = 0; im < 2; ++im)
#pragma unroll
        for (int in = 0; in < 2; ++in) acc[im][in] = (f32x4){0.f,0.f,0.f,0.f};

    for (int k0 = 0; k0 < INPUT_; k0 += 32) {
        short8 af[2], bf[2];
#pragma unroll
        for (int im = 0; im < 2; ++im)
            af[im] = *(const short8*)(xzb + (size_t)(tok0 + wm0 + im*16 + fr) * INPUT_
                                          + k0 + fq * 8);
#pragma unroll
        for (int in = 0; in < 2; ++in)
            bf[in] = *(const short8*)(gw0T + (size_t)(wn0 + in*16 + fr) * INPUT_
                                           + k0 + fq * 8);
#pragma unroll
        for (int im = 0; im < 2; ++im)
#pragma unroll
            for (int in = 0; in < 2; ++in)
                acc[im][in] = __builtin_amdgcn_mfma_f32_16x16x32_bf16(
                    af[im], bf[in], acc[im][in], 0, 0, 0);
    }
    // C layout: col=lane&15, row=(lane>>4)*4+reg
#pragma unroll
    for (int im = 0; im < 2; ++im)
#pragma unroll
        for (int in = 0; in < 2; ++in)
#pragma unroll
            for (int reg = 0; reg < 4; ++reg) {
                int m = wm0 + im*16 + fq*4 + reg;
                int n = wn0 + in*16 + fr;
                float h = acc[im][in][reg] + gb0[n];
                h = h > 0.f ? h : 0.01f * h;
                Hb[m][n] = f2bf(h);
            }
    __syncthreads();

    // ---- g1 MFMA ----
    f32x4 a2[2][2];
#pragma unroll
    for (int im = 0; im < 2; ++im)
#pragma unroll
        for (int in = 0; in < 2; ++in) a2[im][in] = (f32x4){0.f,0.f,0.f,0.f};
#pragma unroll
    for (int k0 = 0; k0 < GATEH; k0 += 32) {
        short8 af[2], bf[2];
#pragma unroll
        for (int im = 0; im < 2; ++im)
            af[im] = *(const short8*)(&Hb[wm0 + im*16 + fr][k0 + fq*8]);
#pragma unroll
        for (int in = 0; in < 2; ++in)
            bf[in] = *(const short8*)(gw1T + (size_t)(wn0 + in*16 + fr) * GATEH
                                           + k0 + fq * 8);
#pragma unroll
        for (int im = 0; im < 2; ++im)
#pragma unroll
            for (int in = 0; in < 2; ++in)
                a2[im][in] = __builtin_amdgcn_mfma_f32_16x16x32_bf16(
                    af[im], bf[in], a2[im][in], 0, 0, 0);
    }
#pragma unroll
    for (int im = 0; im < 2; ++im)
#pragma unroll
        for (int in = 0; in < 2; ++in)
#pragma unroll
            for (int reg = 0; reg < 4; ++reg) {
                int m = wm0 + im*16 + fq*4 + reg;
                int n = wn0 + in*16 + fr;
                float h = a2[im][in][reg] + gb1[n];
                H2[m][n] = h > 0.f ? h : 0.01f * h;
            }
    __syncthreads();

    // ---- g2 (vector): thread -> (tok = tid>>2, 2 experts) ----
    {
        int tok = tid >> 2, e0 = (tid & 3) * 2;
        float l0 = gb2[e0], l1 = gb2[e0 + 1];
#pragma unroll
        for (int i = 0; i < GATEH; ++i) {
            float h = H2[tok][i];
            l0 = fmaf(h, gw2[i * E_ + e0], l0);
            l1 = fmaf(h, gw2[i * E_ + e0 + 1], l1);
        }
        sLg[tok][e0] = l0; sLg[tok][e0 + 1] = l1;
    }
    __syncthreads();

    // ---- softmax + outputs: one thread per token ----
    if (tid < 64) {
        int token = tok0 + tid;
        float lg[E_], m = -1e30f, s = 0.f;
#pragma unroll
        for (int e = 0; e < E_; ++e) { lg[e] = sLg[tid][e]; m = fmaxf(m, lg[e]); }
#pragma unroll
        for (int e = 0; e < E_; ++e) { lg[e] = expf(lg[e] - m); s += lg[e]; }
        float inv = 1.f / s;
        unsigned short pad[KTAIL];
#pragma unroll
        for (int e = 0; e < E_; ++e) {
            float cv = lg[e] * inv;
            coef[(size_t)token * E_ + e] = cv;
            pad[e] = f2bf(cv);
        }
#pragma unroll
        for (int j = E_; j < KTAIL; ++j) pad[j] = 0;
#pragma unroll
        for (int q = 0; q < 4; ++q)
            *(ushort4*)(coefpad + (size_t)token * KTAIL + q * 4) =
                *(const ushort4*)&pad[q * 4];
    }
}

// ---------------------------------------------------------------------------
// Transpose-mix: wmT[b][o][i] = bf16( sum_e coef0[batch0+b][e] * w[e][i][o] )
// for i < fin; K-tail rows i in [fin, fin+32): bias[e][o] (e<8) else 0.
// ---------------------------------------------------------------------------
#define MI 32
#define MO 64
#define MP 65

__global__ __launch_bounds__(256) void mixT_kernel(
    const float* __restrict__ w,          // (E, fin, fout) fp32
    const float* __restrict__ bias,       // (E, fout) fp32
    const float* __restrict__ coef,       // (NTOK, 8)
    unsigned short* __restrict__ wmT,     // (gb, fout, fin+32) bf16
    int fin, int fout, int gb, int batch0)
{
    __shared__ float sW[E_][MI][MP];
    __shared__ float sC[B_][E_];
    const int t = threadIdx.x;
    const int fin_tot = fin + KTAIL;
    const int nbi = fin / MI;
    const int i0 = (blockIdx.x % nbi) * MI;
    const int o0 = (blockIdx.x / nbi) * MO;

    if (t < gb * E_)
        sC[t >> 3][t & 7] = coef[(size_t)(batch0 + (t >> 3)) * T_ * E_ + (t & 7)];

#pragma unroll
    for (int r = 0; r < 64; ++r) {
        int idx = r * 256 + t;
        int o = idx & 63;
        int i = (idx >> 6) & 31;
        int e = idx >> 11;
        sW[e][i][o] = w[(size_t)e * fin * fout + (size_t)(i0 + i) * fout + o0 + o];
    }
    __syncthreads();

    const int o  = t >> 2;
    const int i8 = (t & 3) * 8;
    for (int b = 0; b < gb; ++b) {
        float v[8];
#pragma unroll
        for (int j = 0; j < 8; ++j) v[j] = 0.f;
#pragma unroll
        for (int e = 0; e < E_; ++e) {
            float cc = sC[b][e];
#pragma unroll
            for (int j = 0; j < 8; ++j)
                v[j] = fmaf(cc, sW[e][i8 + j][o], v[j]);
        }
        unsigned short u[8];
#pragma unroll
        for (int j = 0; j < 8; ++j) u[j] = f2bf(v[j]);
        *(int4*)(wmT + ((size_t)b * fout + o0 + o) * fin_tot + i0 + i8) = *(const int4*)u;
    }

    if (i0 == 0) {
        const int jj = t & 3;
        unsigned short u[8];
#pragma unroll
        for (int q = 0; q < 8; ++q)
            u[q] = (jj == 0) ? f2bf(bias[(size_t)q * fout + o0 + o]) : 0;
        for (int b = 0; b < gb; ++b)
            *(int4*)(wmT + ((size_t)b * fout + o0 + o) * fin_tot + fin + jj * 8) =
                *(const int4*)u;
    }
}

// ---------------------------------------------------------------------------
// MFMA GEMM: 128x128 tile, BK=32, 4 waves each 64x64 (4x4 frags).
// XOR-swizzled LDS staging: physical k-group = logical ^ ((rowin>>1)&3),
// compatible with global_load_lds lane scatter; frag reads 2-way max (free).
// A: xz / prev / coefpad (K-tail). B: wmT[b][n][k] (bias in tail rows).
// ---------------------------------------------------------------------------
__global__ __launch_bounds__(256, 3) void gemm_kernel(
    const unsigned short* __restrict__ xz,      // (NTOK, 512) bf16
    const unsigned short* __restrict__ prev,    // (NTOK, 1024) bf16
    const unsigned short* __restrict__ wmT,     // (gb, fout, fin_tot) bf16
    const unsigned short* __restrict__ coefpad, // (NTOK, 32) bf16
    float* __restrict__ outf,                   // fp32 out (layer 4)
    unsigned short* __restrict__ outb,          // bf16 out (layers 0-3), or null
    int fin_tot, int fout, int act, int batch0)
{
    __shared__ __align__(16) unsigned short As[128 * 32];   // 8 KB
    __shared__ __align__(16) unsigned short Bs[128 * 32];   // 8 KB

    const int tid = threadIdx.x;
    const int lane = tid & 63;
    const int wv = tid >> 6;
    const int row0 = blockIdx.y * 128;
    const int col0 = blockIdx.x * 128;
    const size_t tokbase = (size_t)(batch0 + blockIdx.z) * T_;
    const unsigned short* wmb = wmT + (size_t)blockIdx.z * fin_tot * fout;

    f32x4 acc[4][4];
#pragma unroll
    for (int im = 0; im < 4; ++im)
#pragma unroll
        for (int in = 0; in < 4; ++in)
            acc[im][in] = (f32x4){0.f, 0.f, 0.f, 0.f};

    const int lrow = lane >> 2;                              // row in 16-row chunk
    const int lk8  = (((lane & 3) ^ ((lane >> 3) & 3)) * 8); // swizzled k offset
    const int wm0 = (wv & 1) * 64, wn0 = (wv >> 1) * 64;
    const int fr = lane & 15, fq = lane >> 4;
    const int koff = (fq ^ ((fr >> 1) & 3)) * 8;             // swizzled read offset
    const int ktail0 = fin_tot - KTAIL;

    for (int k0 = 0; k0 < fin_tot; k0 += 32) {
        const unsigned short* abase; int astr, acol;
        if (k0 < INPUT_)       { abase = xz;      astr = INPUT_; acol = k0; }
        else if (k0 < ktail0)  { abase = prev;    astr = HIDDEN; acol = k0 - INPUT_; }
        else                   { abase = coefpad; astr = KTAIL;  acol = 0; }

        __syncthreads();   // previous iteration's frag reads complete
#pragma unroll
        for (int q = 0; q < 4; ++q) {
            int ch = wv * 4 + q;   // wave-uniform; 0-7 A chunks, 8-15 B chunks
            const unsigned short* src;
            unsigned short* dst;
            if (ch < 8) {
                int m = ch * 16 + lrow;
                src = abase + (tokbase + row0 + m) * astr + acol + lk8;
                dst = As + ch * 512;
            } else {
                int n = (ch - 8) * 16 + lrow;
                src = wmb + (size_t)(col0 + n) * fin_tot + k0 + lk8;
                dst = Bs + (ch - 8) * 512;
            }
            __builtin_amdgcn_global_load_lds(
                (const __attribute__((address_space(1))) unsigned int*)(const void*)src,
                (__attribute__((address_space(3))) unsigned int*)(void*)dst,
                16, 0, 0);
        }
        __syncthreads();   // drains vmcnt(0): staged data visible

        short8 af[4], bfv[4];
#pragma unroll
        for (int im = 0; im < 4; ++im)
            af[im] = *(const short8*)(As + (wm0 / 16 + im) * 512 + fr * 32 + koff);
#pragma unroll
        for (int in = 0; in < 4; ++in)
            bfv[in] = *(const short8*)(Bs + (wn0 / 16 + in) * 512 + fr * 32 + koff);
#pragma unroll
        for (int im = 0; im < 4; ++im)
#pragma unroll
            for (int in = 0; in < 4; ++in)
                acc[im][in] = __builtin_amdgcn_mfma_f32_16x16x32_bf16(
                    af[im], bfv[in], acc[im][in], 0, 0, 0);
    }

    // epilogue: C/D layout col=lane&15, row=quad*4+reg; leaky + store
#pragma unroll
    for (int im = 0; im < 4; ++im) {
#pragma unroll
        for (int in = 0; in < 4; ++in) {
#pragma unroll
            for (int reg = 0; reg < 4; ++reg) {
                int r = wm0 + im * 16 + fq * 4 + reg;
                int col = wn0 + in * 16 + fr;
                float v = acc[im][in][reg];
                if (act) v = v > 0.f ? v : 0.01f * v;
                size_t off = (tokbase + row0 + r) * fout + col0 + col;
                if (outb) outb[off] = f2bf(v);
                else      outf[off] = v;
            }
        }
    }
}

// ---------------------------------------------------------------------------
// Launch. Workspace: gw0T 64K | gw1T 8K | xz 16.8M | coef 0.5M | cpad 1M |
// actB 33.6M (base ~52.0M); then adaptive gb tier for wmT (+actA at gb=32).
// ---------------------------------------------------------------------------
extern "C" void kernel_launch(void* const* d_in, const int* in_sizes, int n_in,
                              void* d_out, int out_size, void* d_ws, size_t ws_size,
                              hipStream_t stream)
{
    const float* z = (const float*)d_in[0];
    const float* c = (const float*)d_in[1];
    const float* w[5]  = {(const float*)d_in[2], (const float*)d_in[4],
                          (const float*)d_in[6], (const float*)d_in[8],
                          (const float*)d_in[10]};
    const float* bs[5] = {(const float*)d_in[3], (const float*)d_in[5],
                          (const float*)d_in[7], (const float*)d_in[9],
                          (const float*)d_in[11]};
    const float* gw0 = (const float*)d_in[12]; const float* gb0 = (const float*)d_in[13];
    const float* gw1 = (const float*)d_in[14]; const float* gb1 = (const float*)d_in[15];
    const float* gw2 = (const float*)d_in[16]; const float* gb2 = (const float*)d_in[17];

    const size_t g0t_b  = (size_t)GATEH * INPUT_ * 2;   // 64 KB
    const size_t g1t_b  = (size_t)GATEH * GATEH * 2;    // 8 KB
    const size_t xz_b   = (size_t)NTOK * INPUT_ * 2;
    const size_t coef_b = (size_t)NTOK * E_ * 4;
    const size_t cpad_b = (size_t)NTOK * KTAIL * 2;
    const size_t act_b  = (size_t)NTOK * HIDDEN * 2;
    const size_t wmun   = (size_t)(INTER_ + KTAIL) * HIDDEN * 2;  // per-batch max

    char* p = (char*)d_ws;
    unsigned short* gw0T  = (unsigned short*)p;  p += g0t_b;
    unsigned short* gw1T  = (unsigned short*)p;  p += g1t_b;
    unsigned short* xzb   = (unsigned short*)p;  p += xz_b;
    float*          coef  = (float*)p;           p += coef_b;
    unsigned short* cpad  = (unsigned short*)p;  p += cpad_b;
    unsigned short* actB  = (unsigned short*)p;  p += act_b;

    size_t base = g0t_b + g1t_b + xz_b + coef_b + cpad_b + act_b;
    size_t avail = (ws_size > base) ? ws_size - base : 0;

    int gb;
    unsigned short* actA;
    unsigned short* wmT;
    if (avail >= act_b + 32 * wmun) {
        gb = 32; actA = (unsigned short*)p; p += act_b; wmT = (unsigned short*)p;
    } else {
        actA = (unsigned short*)d_out;
        wmT  = (unsigned short*)p;
        gb = 1;
        for (int g = 16; g >= 2; g >>= 1)
            if (avail >= (size_t)g * wmun) { gb = g; break; }
    }

    wprep_kernel<<<(GATEH * (INPUT_ + GATEH) + 255) / 256, 256, 0, stream>>>(
        gw0, gw1, gw0T, gw1T);
    gate_kernel<<<NTOK / 64, 256, 0, stream>>>(
        z, c, gb0, gb1, gw2, gb2, gw0T, gw1T, coef, cpad, xzb);

    struct L { int fin, fout, act; const unsigned short* in; unsigned short* outb; };
    L Ls[5] = {
        {INPUT_, HIDDEN, 1, actB /*unused*/, actA},
        {INTER_, HIDDEN, 1, actA, actB},
        {INTER_, HIDDEN, 1, actB, actA},
        {INTER_, HIDDEN, 1, actA, actB},
        {INTER_, OUTD,   0, actB, 0},
    };

    for (int Li = 0; Li < 5; ++Li) {
        int fin = Ls[Li].fin, fout = Ls[Li].fout;
        int nblk = (fin / MI) * (fout / MO);
        for (int g = 0; g < B_; g += gb) {
            mixT_kernel<<<nblk, 256, 0, stream>>>(
                w[Li], bs[Li], coef, wmT, fin, fout, gb, g);
            gemm_kernel<<<dim3(fout / 128, T_ / 128, gb), 256, 0, stream>>>(
                xzb, Ls[Li].in, wmT, cpad,
                (float*)d_out, Ls[Li].outb, fin + KTAIL, fout, Ls[Li].act, g);
        }
    }
}